// Round 12
// baseline (334.271 us; speedup 1.0000x reference)
//
#include <hip/hip_runtime.h>

// Problem constants
#define HQn   16
#define HKVn  4
#define HDn   64
#define SEQN  4096
#define NB    2
#define DM    1024
#define KVD   256
#define NPACK 1536   // packed QKV output cols: 1024 Q | 256 K | 256 V

// Q pre-scale: 1/sqrt(64) * log2(e)  -> softmax runs in exp2 domain
#define QSCALE 0.18033688011112042f

typedef __attribute__((ext_vector_type(8))) short short8;   // 8 x bf16 (4 VGPRs) MFMA operand
typedef __attribute__((ext_vector_type(4))) float f32x4;    // MFMA accumulator

#define MFMA16 __builtin_amdgcn_mfma_f32_16x16x32_bf16
#define EXP2F(x) __builtin_amdgcn_exp2f(x)

// float -> bf16 round-to-nearest-even
static __device__ __forceinline__ unsigned short f2bf(float f){
  union { float f; unsigned int u; } c; c.f = f;
  unsigned int r = c.u + 0x7fffu + ((c.u >> 16) & 1u);
  return (unsigned short)(r >> 16);
}

// pack two floats to bf16x2 — single v_cvt_pk_bf16_f32 on gfx950 (a=low, b=high)
#if __has_builtin(__builtin_amdgcn_cvt_pk_bf16_f32)
typedef __attribute__((ext_vector_type(2))) __bf16 bf16x2v;
static __device__ __forceinline__ unsigned int pk_bf2(float a, float b){
  union { bf16x2v v; unsigned int u; } c;
  c.v = __builtin_amdgcn_cvt_pk_bf16_f32(a, b);
  return c.u;
}
#else
static __device__ __forceinline__ unsigned int pk_bf2(float a, float b){
  union { float f; unsigned int u; } ca, cb; ca.f = a; cb.f = b;
  return ((ca.u + 0x8000u) >> 16) | ((cb.u + 0x8000u) & 0xFFFF0000u);
}
#endif

// async global->LDS, 16 bytes per lane (wave-uniform base + lane*16 dest)
static __device__ __forceinline__ void gl2lds16(const void* g, void* l){
  __builtin_amdgcn_global_load_lds(
      (const __attribute__((address_space(1))) void*)g,
      (__attribute__((address_space(3))) void*)l, 16, 0, 0);
}

// ---------------------------------------------------------------------------
// Kernel 0: RoPE tables, precise sinf/cosf to match the fp32 reference.
// ---------------------------------------------------------------------------
__global__ void rope_tables_k(float* __restrict__ ct, float* __restrict__ st){
  int t = blockIdx.x, d = threadIdx.x;
  int i = d & 31;
  float inv = 1.0f / powf(10000.0f, (float)i * (1.0f/32.0f));
  float ang = (float)t * inv;
  ct[t*HDn + d] = cosf(ang);
  st[t*HDn + d] = sinf(ang);
}

// ---------------------------------------------------------------------------
// Kernel 0b: cast x fp32 -> bf16 (row-major unchanged), 8 elems/thread.
// ---------------------------------------------------------------------------
__global__ __launch_bounds__(256) void castx_k(const float* __restrict__ x,
                                               unsigned short* __restrict__ xb){
  size_t i = ((size_t)blockIdx.x * 256 + threadIdx.x) * 8;
  float4 a = *(const float4*)(x + i);
  float4 b = *(const float4*)(x + i + 4);
  short8 o;
  o[0]=f2bf(a.x); o[1]=f2bf(a.y); o[2]=f2bf(a.z); o[3]=f2bf(a.w);
  o[4]=f2bf(b.x); o[5]=f2bf(b.y); o[6]=f2bf(b.z); o[7]=f2bf(b.w);
  *(short8*)(xb + i) = o;
}

// ---------------------------------------------------------------------------
// Kernel 0c: transpose-cast weights into B^T bf16 layout.
// ---------------------------------------------------------------------------
__global__ __launch_bounds__(256) void castw_k(
    const float* __restrict__ Wq, const float* __restrict__ Wk,
    const float* __restrict__ Wv, const float* __restrict__ Wo,
    unsigned short* __restrict__ Wqkv_t, unsigned short* __restrict__ Wot)
{
  const int z = blockIdx.z;
  const float* W; unsigned short* D; int srcN, nOff;
  if      (z == 0) { W = Wq; D = Wqkv_t; srcN = DM;  nOff = 0;    }
  else if (z == 1) { W = Wo; D = Wot;    srcN = DM;  nOff = 0;    }
  else if (z == 2) { W = Wk; D = Wqkv_t; srcN = KVD; nOff = 1024; }
  else             { W = Wv; D = Wqkv_t; srcN = KVD; nOff = 1280; }
  const int n0 = blockIdx.y * 64;
  if (n0 >= srcN) return;
  const int k0 = blockIdx.x * 64;
  const int tid = threadIdx.x;

  __shared__ float tile[64][65];
  const int lr = tid >> 4, lc = (tid & 15) * 4;
  #pragma unroll
  for (int p = 0; p < 4; p++) {
    float4 v = *(const float4*)&W[(size_t)(k0 + lr + p*16) * srcN + n0 + lc];
    tile[lr + p*16][lc+0] = v.x; tile[lr + p*16][lc+1] = v.y;
    tile[lr + p*16][lc+2] = v.z; tile[lr + p*16][lc+3] = v.w;
  }
  __syncthreads();

  const int nn = tid >> 2, kc = (tid & 3) * 16;
  unsigned short* dp = D + (size_t)(nOff + n0 + nn) * DM + k0 + kc;
  #pragma unroll
  for (int q = 0; q < 4; q++) {
    ushort4 o;
    o.x = f2bf(tile[kc + q*4 + 0][nn]);
    o.y = f2bf(tile[kc + q*4 + 1][nn]);
    o.z = f2bf(tile[kc + q*4 + 2][nn]);
    o.w = f2bf(tile[kc + q*4 + 3][nn]);
    *(ushort4*)(dp + q*4) = o;
  }
}

// ---------------------------------------------------------------------------
// Kernel 1: fused QKV GEMM + RoPE epilogue. R11's double-buffer upgraded to
// TRIPLE-buffer + counted vmcnt (T4): prefetch runs 2 tiles deep; the
// end-of-iter wait is `s_waitcnt vmcnt(4)` + raw s_barrier — it retires
// exactly the oldest stage (tile t+1, issued a FULL iteration earlier,
// ~2 compute phases ≈ 1300 cyc of cover for HBM misses) while the newest
// stage stays in flight across the barrier (never vmcnt(0) in-loop).
// Ledger: per-thread 4 gl2lds/stage; at wait, outstanding = t+1(4)+t+2(4)=8
// -> vmcnt(4) == tile t+1 complete. Reads of buf[t%3] are register-consumed
// (lgkm-drained before their MFMAs) before barrier t; next write to that
// buffer issues after barrier t. Tail iters (no stage) wait vmcnt(0).
// "memory"-clobber asm before the raw barrier pins gl2lds and next-iter
// ds_reads. LDS 48 KB -> 3 blocks/CU cap (grid gives 3).
// ---------------------------------------------------------------------------
__global__ __launch_bounds__(256) void qkv2_k(
    const unsigned short* __restrict__ A, const unsigned short* __restrict__ Bt,
    const float* __restrict__ ct, const float* __restrict__ st,
    unsigned short* __restrict__ Qo, unsigned short* __restrict__ Ko,
    unsigned short* __restrict__ Vo)
{
  __shared__ __align__(16) short As[3][128][32];
  __shared__ __align__(16) short Bs[3][128][32];

  const int m0 = blockIdx.x * 128, n0 = blockIdx.y * 128;
  const int tid = threadIdx.x, lane = tid & 63, w = tid >> 6;
  const int wm = w >> 1, wn = w & 1;
  const int ln = lane & 15, quad = lane >> 4;

  f32x4 acc[4][4];
  #pragma unroll
  for (int i = 0; i < 4; i++)
    #pragma unroll
    for (int j = 0; j < 4; j++) acc[i][j] = (f32x4){0.f,0.f,0.f,0.f};

  const int r0 = tid >> 2, c8 = (tid & 3) * 8;
  const int r1 = r0 + 64;

  #define GSTAGE(cn, kk)                                                     \
    do {                                                                     \
      gl2lds16(A  + (size_t)(m0 + r0)*DM + (kk) + c8, &As[cn][r0][c8]);      \
      gl2lds16(A  + (size_t)(m0 + r1)*DM + (kk) + c8, &As[cn][r1][c8]);      \
      gl2lds16(Bt + (size_t)(n0 + r0)*DM + (kk) + c8, &Bs[cn][r0][c8]);      \
      gl2lds16(Bt + (size_t)(n0 + r1)*DM + (kk) + c8, &Bs[cn][r1][c8]);      \
    } while (0)

  GSTAGE(0, 0);
  GSTAGE(1, 32);
  asm volatile("s_waitcnt vmcnt(4)" ::: "memory");   // buf0 complete
  __builtin_amdgcn_s_barrier();

  int cb = 0;
  for (int k0 = 0; k0 < DM; k0 += 32) {
    int nb2 = cb + 2; if (nb2 >= 3) nb2 -= 3;
    const bool staged = (k0 + 64 < DM);
    if (staged) GSTAGE(nb2, k0 + 64);

    short8 af[4], bf[4];
    #pragma unroll
    for (int mb = 0; mb < 4; mb++) af[mb] = *(const short8*)&As[cb][wm*64 + mb*16 + ln][quad*8];
    #pragma unroll
    for (int nb = 0; nb < 4; nb++) bf[nb] = *(const short8*)&Bs[cb][wn*64 + nb*16 + ln][quad*8];
    #pragma unroll
    for (int mb = 0; mb < 4; mb++)
      #pragma unroll
      for (int nb = 0; nb < 4; nb++)
        acc[mb][nb] = MFMA16(af[mb], bf[nb], acc[mb][nb], 0, 0, 0);

    if (k0 + 32 < DM) {
      if (staged) asm volatile("s_waitcnt vmcnt(4)" ::: "memory");
      else        asm volatile("s_waitcnt vmcnt(0)" ::: "memory");
      __builtin_amdgcn_s_barrier();
    }
    cb = cb + 1; if (cb >= 3) cb -= 3;
  }
  #undef GSTAGE

  const int nc = n0 + wn*64;
  int kind, head;
  if (nc < 1024)      { kind = 0; head = nc >> 6;          }
  else if (nc < 1280) { kind = 1; head = (nc - 1024) >> 6; }
  else                { kind = 2; head = (nc - 1280) >> 6; }

  if (kind == 2) {
    #pragma unroll
    for (int mb = 0; mb < 4; mb++) {
      const int m = m0 + wm*64 + mb*16 + quad*4;
      const int t = m & (SEQN-1), b = m >> 12;
      #pragma unroll
      for (int nb = 0; nb < 4; nb++) {
        int d = nb*16 + ln;
        ushort4 pk;
        pk.x = f2bf(acc[mb][nb][0]); pk.y = f2bf(acc[mb][nb][1]);
        pk.z = f2bf(acc[mb][nb][2]); pk.w = f2bf(acc[mb][nb][3]);
        *(ushort4*)&Vo[(((size_t)(b*HKVn + head))*HDn + d)*SEQN + t] = pk;
      }
    }
  } else {
    #pragma unroll
    for (int mb = 0; mb < 4; mb++) {
      #pragma unroll
      for (int nb = 0; nb < 4; nb++) {
        #pragma unroll
        for (int r = 0; r < 4; r++) {
          int m = m0 + wm*64 + mb*16 + quad*4 + r;
          int t = m & (SEQN-1), b = m >> 12;
          int d = nb*16 + ln;
          float v = acc[mb][nb][r];
          float partner = (nb < 2) ? -acc[mb][nb+2][r] : acc[mb][nb-2][r];
          float cv = ct[t*HDn + d], sv = st[t*HDn + d];
          float o = v*cv + partner*sv;
          if (kind == 0) Qo[(((size_t)(b*HQn  + head))*SEQN + t)*HDn + d] = f2bf(o * QSCALE);
          else           Ko[(((size_t)(b*HKVn + head))*SEQN + t)*HDn + d] = f2bf(o);
        }
      }
    }
  }
}

// ---------------------------------------------------------------------------
// Kernel 2: flash attention — ROUND-7 VERSION VERBATIM (154 us, verified 3x):
// async gl2lds staging, XOR-swizzled unpadded double buffers, 1 barrier/tile,
// permlane-free K staging interleave, MFMA-of-ones row-sum, setprio.
// ---------------------------------------------------------------------------
__global__ __launch_bounds__(256, 4) void attn_k(
    const unsigned short* __restrict__ Q, const unsigned short* __restrict__ K,
    const unsigned short* __restrict__ Vt, unsigned short* __restrict__ AO)
{
  __shared__ __align__(16) short kb[2][64][64];   // 8 KB per buf
  __shared__ __align__(16) short vb[2][64][64];   // 8 KB per buf

  const int id  = blockIdx.x;
  const int bhv = id & 7;               // XCD-affine: XCD (id%8) owns one (b,hv)
  const int b   = bhv >> 2, hv = bhv & 3;
  const int rem = id >> 3;
  const int qt  = rem & 31;
  const int h   = hv*4 + (rem >> 5);
  const int q0  = qt * 128;

  const int tid = threadIdx.x, lane = tid & 63, w = tid >> 6;
  const int ln = lane & 15, quad = lane >> 4;

  const unsigned short* Qp = Q + (((size_t)(b*HQn + h))*SEQN + q0 + w*32) * HDn;
  const unsigned short* Kp = K + ((size_t)(b*HKVn + hv))*SEQN * HDn;
  const unsigned short* Vp = Vt + ((size_t)(b*HKVn + hv))*HDn * SEQN;

  short8 qf[2][2];
  qf[0][0] = *(const short8*)(Qp + ln*HDn + quad*8);
  qf[0][1] = *(const short8*)(Qp + ln*HDn + 32 + quad*8);
  qf[1][0] = *(const short8*)(Qp + (16+ln)*HDn + quad*8);
  qf[1][1] = *(const short8*)(Qp + (16+ln)*HDn + 32 + quad*8);

  short8 ones;
  #pragma unroll
  for (int j = 0; j < 8; j++) ones[j] = (short)0x3F80;   // bf16 1.0

  f32x4 o[2][4], lacc[2];
  #pragma unroll
  for (int g = 0; g < 2; g++) {
    #pragma unroll
    for (int i = 0; i < 4; i++) o[g][i] = (f32x4){0.f,0.f,0.f,0.f};
    lacc[g] = (f32x4){0.f,0.f,0.f,0.f};
  }

  // --- staging geometry: waves 0,1 stage K; waves 2,3 stage V. ---
  const int w2   = w & 1;        // half (rows 0-31 / 32-63)
  const int lrow = lane >> 3;    // row within 8-row chunk (== row&7)
  const int slin = lane & 7;     // linear 16B slot within row
  const int sK   = slin ^ lrow;  // swizzled source slot (involution)

  // K uses the PERMLANE-FREE interleave (round 7, verified):
  // kb row R = w2*32 + i*8 + lrow holds key_stage(R)
  //   = 32*w2 + 16*(i&1) + 8*(lrow>>2) + 4*(i>>1) + (lrow&3)
  int kkey[4]; size_t vrow[4];
  #pragma unroll
  for (int i = 0; i < 4; i++) {
    kkey[i] = 32*w2 + 16*(i & 1) + 8*(lrow >> 2) + 4*(i >> 1) + (lrow & 3);
    vrow[i] = (size_t)(w2*32 + i*8 + lrow) * SEQN;
  }

  #define STAGE(cn, kts)                                                     \
    do {                                                                     \
      if (w < 2) {                                                           \
        _Pragma("unroll")                                                    \
        for (int i = 0; i < 4; i++)                                          \
          gl2lds16(Kp + (size_t)((kts) + kkey[i])*HDn + sK*8,                \
                   &kb[cn][w2*32 + i*8][0]);                                 \
      } else {                                                               \
        _Pragma("unroll")                                                    \
        for (int i = 0; i < 4; i++)                                          \
          gl2lds16(Vp + vrow[i] + (kts) + sK*8,                              \
                   &vb[cn][w2*32 + i*8][0]);                                 \
      }                                                                      \
    } while (0)

  // swizzled read offsets (shorts within a row); row&7 == ln&7 for all reads
  const int swz0 = (( quad      ^ (ln & 7)) * 8);
  const int swz1 = (((quad + 4) ^ (ln & 7)) * 8);

  STAGE(0, 0);
  __syncthreads();

  int c = 0;
  for (int kt = 0; kt < SEQN; kt += 64) {
    if (kt + 64 < SEQN) STAGE(c ^ 1, kt + 64);

    // phase 1: swapped QK^T for both g, K fragments read once (8 ds_read_b128)
    // s[g][nb][r] = S[key = 32*(nb>>1) + 8*quad + 4*(nb&1) + r][qrow = ln]
    f32x4 s[2][4];
    __builtin_amdgcn_s_setprio(1);
    #pragma unroll
    for (int nb = 0; nb < 4; nb++) {
      short8 k0 = *(const short8*)&kb[c][nb*16 + ln][swz0];
      short8 k1 = *(const short8*)&kb[c][nb*16 + ln][swz1];
      f32x4 t0 = (f32x4){0.f,0.f,0.f,0.f};
      t0 = MFMA16(k0, qf[0][0], t0, 0, 0, 0);
      t0 = MFMA16(k1, qf[0][1], t0, 0, 0, 0);
      s[0][nb] = t0;
      f32x4 t1 = (f32x4){0.f,0.f,0.f,0.f};
      t1 = MFMA16(k0, qf[1][0], t1, 0, 0, 0);
      t1 = MFMA16(k1, qf[1][1], t1, 0, 0, 0);
      s[1][nb] = t1;
    }
    __builtin_amdgcn_s_setprio(0);

    // exp2 + cvt_pk: PV A-fragments directly from the lane's own registers
    short8 pf[2][2];
    #pragma unroll
    for (int g = 0; g < 2; g++) {
      #pragma unroll
      for (int k2 = 0; k2 < 2; k2++) {
        union { short8 s8; unsigned u[4]; } f;
        f.u[0] = pk_bf2(EXP2F(s[g][2*k2  ][0]), EXP2F(s[g][2*k2  ][1]));
        f.u[1] = pk_bf2(EXP2F(s[g][2*k2  ][2]), EXP2F(s[g][2*k2  ][3]));
        f.u[2] = pk_bf2(EXP2F(s[g][2*k2+1][0]), EXP2F(s[g][2*k2+1][1]));
        f.u[3] = pk_bf2(EXP2F(s[g][2*k2+1][2]), EXP2F(s[g][2*k2+1][3]));
        pf[g][k2] = f.s8;
      }
    }

    // phase 2: P x V^T for both g, V fragments read once (8 ds_read_b128)
    __builtin_amdgcn_s_setprio(1);
    #pragma unroll
    for (int db = 0; db < 4; db++) {
      short8 v0 = *(const short8*)&vb[c][db*16 + ln][swz0];
      short8 v1 = *(const short8*)&vb[c][db*16 + ln][swz1];
      o[0][db] = MFMA16(pf[0][0], v0, o[0][db], 0, 0, 0);
      o[0][db] = MFMA16(pf[0][1], v1, o[0][db], 0, 0, 0);
      o[1][db] = MFMA16(pf[1][0], v0, o[1][db], 0, 0, 0);
      o[1][db] = MFMA16(pf[1][1], v1, o[1][db], 0, 0, 0);
    }
    lacc[0] = MFMA16(pf[0][0], ones, lacc[0], 0, 0, 0);
    lacc[0] = MFMA16(pf[0][1], ones, lacc[0], 0, 0, 0);
    lacc[1] = MFMA16(pf[1][0], ones, lacc[1], 0, 0, 0);
    lacc[1] = MFMA16(pf[1][1], ones, lacc[1], 0, 0, 0);
    __builtin_amdgcn_s_setprio(0);

    __syncthreads();   // vmcnt(0): drains next-tile stage (covered by compute)
    c ^= 1;
  }
  #undef STAGE

  #pragma unroll
  for (int g = 0; g < 2; g++) {
    float inv[4];
    #pragma unroll
    for (int r = 0; r < 4; r++) inv[r] = 1.0f / lacc[g][r];
    #pragma unroll
    for (int db = 0; db < 4; db++) {
      #pragma unroll
      for (int r = 0; r < 4; r++) {
        int gq = q0 + w*32 + g*16 + quad*4 + r;
        int d  = db*16 + ln;
        AO[(((size_t)(b*SEQN + gq))*HQn + h)*HDn + d] = f2bf(o[g][db][r] * inv[r]);
      }
    }
  }
}

// ---------------------------------------------------------------------------
// Kernel 3: output projection — same triple-buffer + counted-vmcnt upgrade.
// ---------------------------------------------------------------------------
__global__ __launch_bounds__(256) void oproj2_k(
    const unsigned short* __restrict__ A, const unsigned short* __restrict__ Bt,
    float* __restrict__ out)
{
  __shared__ __align__(16) short As[3][128][32];
  __shared__ __align__(16) short Bs[3][128][32];

  const int m0 = blockIdx.x * 128, n0 = blockIdx.y * 128;
  const int tid = threadIdx.x, lane = tid & 63, w = tid >> 6;
  const int wm = w >> 1, wn = w & 1;
  const int ln = lane & 15, quad = lane >> 4;

  f32x4 acc[4][4];
  #pragma unroll
  for (int i = 0; i < 4; i++)
    #pragma unroll
    for (int j = 0; j < 4; j++) acc[i][j] = (f32x4){0.f,0.f,0.f,0.f};

  const int r0 = tid >> 2, c8 = (tid & 3) * 8;
  const int r1 = r0 + 64;

  #define GSTAGE(cn, kk)                                                     \
    do {                                                                     \
      gl2lds16(A  + (size_t)(m0 + r0)*DM + (kk) + c8, &As[cn][r0][c8]);      \
      gl2lds16(A  + (size_t)(m0 + r1)*DM + (kk) + c8, &As[cn][r1][c8]);      \
      gl2lds16(Bt + (size_t)(n0 + r0)*DM + (kk) + c8, &Bs[cn][r0][c8]);      \
      gl2lds16(Bt + (size_t)(n0 + r1)*DM + (kk) + c8, &Bs[cn][r1][c8]);      \
    } while (0)

  GSTAGE(0, 0);
  GSTAGE(1, 32);
  asm volatile("s_waitcnt vmcnt(4)" ::: "memory");   // buf0 complete
  __builtin_amdgcn_s_barrier();

  int cb = 0;
  for (int k0 = 0; k0 < DM; k0 += 32) {
    int nb2 = cb + 2; if (nb2 >= 3) nb2 -= 3;
    const bool staged = (k0 + 64 < DM);
    if (staged) GSTAGE(nb2, k0 + 64);

    short8 af[4], bf[4];
    #pragma unroll
    for (int mb = 0; mb < 4; mb++) af[mb] = *(const short8*)&As[cb][wm*64 + mb*16 + ln][quad*8];
    #pragma unroll
    for (int nb = 0; nb < 4; nb++) bf[nb] = *(const short8*)&Bs[cb][wn*64 + nb*16 + ln][quad*8];
    #pragma unroll
    for (int mb = 0; mb < 4; mb++)
      #pragma unroll
      for (int nb = 0; nb < 4; nb++)
        acc[mb][nb] = MFMA16(af[mb], bf[nb], acc[mb][nb], 0, 0, 0);

    if (k0 + 32 < DM) {
      if (staged) asm volatile("s_waitcnt vmcnt(4)" ::: "memory");
      else        asm volatile("s_waitcnt vmcnt(0)" ::: "memory");
      __builtin_amdgcn_s_barrier();
    }
    cb = cb + 1; if (cb >= 3) cb -= 3;
  }
  #undef GSTAGE

  #pragma unroll
  for (int mb = 0; mb < 4; mb++) {
    #pragma unroll
    for (int nb = 0; nb < 4; nb++) {
      #pragma unroll
      for (int r = 0; r < 4; r++) {
        int m = m0 + wm*64 + mb*16 + quad*4 + r;
        int c = n0 + wn*64 + nb*16 + ln;
        out[(size_t)m*DM + c] = acc[mb][nb][r];
      }
    }
  }
}

// ---------------------------------------------------------------------------
extern "C" void kernel_launch(void* const* d_in, const int* in_sizes, int n_in,
                              void* d_out, int out_size, void* d_ws, size_t ws_size,
                              hipStream_t stream) {
  const float* x  = (const float*)d_in[0];
  const float* Wq = (const float*)d_in[1];
  const float* Wk = (const float*)d_in[2];
  const float* Wv = (const float*)d_in[3];
  const float* Wo = (const float*)d_in[4];
  float* out = (float*)d_out;

  // workspace layout (47 MB). AO aliases xb (xb dead after qkv2_k).
  char* ws = (char*)d_ws;
  float* cos_t = (float*)ws;                                   // 1 MB
  float* sin_t = cos_t + SEQN*HDn;                             // 1 MB
  unsigned short* xb     = (unsigned short*)(sin_t + SEQN*HDn);   // 16 MB
  unsigned short* AO     = xb;                                    // alias
  unsigned short* Wqkv_t = xb + (size_t)NB*SEQN*DM;               // 3 MB
  unsigned short* Wot    = Wqkv_t + (size_t)NPACK*DM;             // 2 MB
  unsigned short* Qb     = Wot + (size_t)DM*DM;                   // 16 MB
  unsigned short* Kb     = Qb + (size_t)NB*HQn *SEQN*HDn;         // 4 MB
  unsigned short* Vb     = Kb + (size_t)NB*HKVn*SEQN*HDn;         // 4 MB

  hipLaunchKernelGGL(rope_tables_k, dim3(SEQN), dim3(HDn), 0, stream, cos_t, sin_t);
  hipLaunchKernelGGL(castx_k, dim3((NB*SEQN*DM)/(256*8)), dim3(256), 0, stream, x, xb);
  hipLaunchKernelGGL(castw_k, dim3(16, 16, 4), dim3(256), 0, stream,
                     Wq, Wk, Wv, Wo, Wqkv_t, Wot);
  hipLaunchKernelGGL(qkv2_k, dim3(64, 12), dim3(256), 0, stream,
                     xb, Wqkv_t, cos_t, sin_t, Qb, Kb, Vb);
  hipLaunchKernelGGL(attn_k, dim3(1024), dim3(256), 0, stream,
                     Qb, Kb, Vb, AO);
  hipLaunchKernelGGL(oproj2_k, dim3(64, 8), dim3(256), 0, stream,
                     AO, Wot, out);
}

// Round 13
// 290.223 us; speedup vs baseline: 1.1518x; 1.1518x over previous
//
#include <hip/hip_runtime.h>

// Problem constants
#define HQn   16
#define HKVn  4
#define HDn   64
#define SEQN  4096
#define NB    2
#define DM    1024
#define KVD   256
#define NPACK 1536   // packed QKV output cols: 1024 Q | 256 K | 256 V

// Q pre-scale: 1/sqrt(64) * log2(e)  -> softmax runs in exp2 domain
#define QSCALE 0.18033688011112042f

typedef __attribute__((ext_vector_type(8))) short short8;   // 8 x bf16 (4 VGPRs) MFMA operand
typedef __attribute__((ext_vector_type(4))) float f32x4;    // MFMA accumulator

#define MFMA16 __builtin_amdgcn_mfma_f32_16x16x32_bf16
#define EXP2F(x) __builtin_amdgcn_exp2f(x)

// float -> bf16 round-to-nearest-even
static __device__ __forceinline__ unsigned short f2bf(float f){
  union { float f; unsigned int u; } c; c.f = f;
  unsigned int r = c.u + 0x7fffu + ((c.u >> 16) & 1u);
  return (unsigned short)(r >> 16);
}

// pack two floats to bf16x2 — single v_cvt_pk_bf16_f32 on gfx950 (a=low, b=high)
#if __has_builtin(__builtin_amdgcn_cvt_pk_bf16_f32)
typedef __attribute__((ext_vector_type(2))) __bf16 bf16x2v;
static __device__ __forceinline__ unsigned int pk_bf2(float a, float b){
  union { bf16x2v v; unsigned int u; } c;
  c.v = __builtin_amdgcn_cvt_pk_bf16_f32(a, b);
  return c.u;
}
#else
static __device__ __forceinline__ unsigned int pk_bf2(float a, float b){
  union { float f; unsigned int u; } ca, cb; ca.f = a; cb.f = b;
  return ((ca.u + 0x8000u) >> 16) | ((cb.u + 0x8000u) & 0xFFFF0000u);
}
#endif

// async global->LDS, 16 bytes per lane (wave-uniform base + lane*16 dest)
static __device__ __forceinline__ void gl2lds16(const void* g, void* l){
  __builtin_amdgcn_global_load_lds(
      (const __attribute__((address_space(1))) void*)g,
      (__attribute__((address_space(3))) void*)l, 16, 0, 0);
}

// ---------------------------------------------------------------------------
// Kernel 0 (merged prep): rope tables + x cast + weight transpose-cast in a
// single launch. Block ranges:
//   [0, 1024)            rope: idx = id*256+tid; t = idx>>6, d = idx&63
//   [1024, 5120)         castx: 8 elems/thread (R11 castx_k body)
//   [5120, 6144)         castw: cid = id-5120; z = cid&3, by = (cid>>2)&15,
//                        bx = cid>>6   (same ranges as the old (16,16,4) grid)
// Bodies are byte-identical to the verified standalone kernels; only the
// index decomposition changed. Saves 2 kernel-launch gaps and runs rope at
// 256-thread blocks instead of 64.
// ---------------------------------------------------------------------------
__global__ __launch_bounds__(256) void prep_k(
    const float* __restrict__ x,
    const float* __restrict__ Wq, const float* __restrict__ Wk,
    const float* __restrict__ Wv, const float* __restrict__ Wo,
    float* __restrict__ ct, float* __restrict__ st,
    unsigned short* __restrict__ xb,
    unsigned short* __restrict__ Wqkv_t, unsigned short* __restrict__ Wot)
{
  const int id = blockIdx.x, tid = threadIdx.x;
  __shared__ float tile[64][65];   // used by castw branch only

  if (id < 1024) {
    // --- rope tables ---
    int idx = id * 256 + tid;
    int t = idx >> 6, d = idx & 63;
    int i = d & 31;
    float inv = 1.0f / powf(10000.0f, (float)i * (1.0f/32.0f));
    float ang = (float)t * inv;
    ct[t*HDn + d] = cosf(ang);
    st[t*HDn + d] = sinf(ang);
    return;
  }

  if (id < 5120) {
    // --- cast x fp32 -> bf16, 8 elems/thread ---
    size_t i = ((size_t)(id - 1024) * 256 + tid) * 8;
    float4 a = *(const float4*)(x + i);
    float4 b = *(const float4*)(x + i + 4);
    short8 o;
    o[0]=f2bf(a.x); o[1]=f2bf(a.y); o[2]=f2bf(a.z); o[3]=f2bf(a.w);
    o[4]=f2bf(b.x); o[5]=f2bf(b.y); o[6]=f2bf(b.z); o[7]=f2bf(b.w);
    *(short8*)(xb + i) = o;
    return;
  }

  // --- transpose-cast weights into B^T bf16 layout ---
  const int cid = id - 5120;
  const int z = cid & 3;
  const int by = (cid >> 2) & 15;
  const int bx = cid >> 6;

  const float* W; unsigned short* D; int srcN, nOff;
  if      (z == 0) { W = Wq; D = Wqkv_t; srcN = DM;  nOff = 0;    }
  else if (z == 1) { W = Wo; D = Wot;    srcN = DM;  nOff = 0;    }
  else if (z == 2) { W = Wk; D = Wqkv_t; srcN = KVD; nOff = 1024; }
  else             { W = Wv; D = Wqkv_t; srcN = KVD; nOff = 1280; }
  const int n0 = by * 64;
  if (n0 >= srcN) return;
  const int k0 = bx * 64;

  const int lr = tid >> 4, lc = (tid & 15) * 4;
  #pragma unroll
  for (int p = 0; p < 4; p++) {
    float4 v = *(const float4*)&W[(size_t)(k0 + lr + p*16) * srcN + n0 + lc];
    tile[lr + p*16][lc+0] = v.x; tile[lr + p*16][lc+1] = v.y;
    tile[lr + p*16][lc+2] = v.z; tile[lr + p*16][lc+3] = v.w;
  }
  __syncthreads();

  const int nn = tid >> 2, kc = (tid & 3) * 16;
  unsigned short* dp = D + (size_t)(nOff + n0 + nn) * DM + k0 + kc;
  #pragma unroll
  for (int q = 0; q < 4; q++) {
    ushort4 o;
    o.x = f2bf(tile[kc + q*4 + 0][nn]);
    o.y = f2bf(tile[kc + q*4 + 1][nn]);
    o.z = f2bf(tile[kc + q*4 + 2][nn]);
    o.w = f2bf(tile[kc + q*4 + 3][nn]);
    *(ushort4*)(dp + q*4) = o;
  }
}

// ---------------------------------------------------------------------------
// Kernel 1: fused QKV GEMM + RoPE epilogue — R11 VERSION VERBATIM (verified
// 303 us total): double-buffered LDS, prefetch-before-compute, ONE
// __syncthreads per K-step. (R12's triple-buffer + manual counted vmcnt
// regressed: the "memory"-clobber asm + raw barriers pinned the compiler
// scheduler — m141 anti-pattern. The compiler-scheduled double buffer with
// one-phase-covered drain is the sweet spot for this structure.)
// ---------------------------------------------------------------------------
__global__ __launch_bounds__(256) void qkv2_k(
    const unsigned short* __restrict__ A, const unsigned short* __restrict__ Bt,
    const float* __restrict__ ct, const float* __restrict__ st,
    unsigned short* __restrict__ Qo, unsigned short* __restrict__ Ko,
    unsigned short* __restrict__ Vo)
{
  __shared__ __align__(16) short As[2][128][32];
  __shared__ __align__(16) short Bs[2][128][32];

  const int m0 = blockIdx.x * 128, n0 = blockIdx.y * 128;
  const int tid = threadIdx.x, lane = tid & 63, w = tid >> 6;
  const int wm = w >> 1, wn = w & 1;
  const int ln = lane & 15, quad = lane >> 4;

  f32x4 acc[4][4];
  #pragma unroll
  for (int i = 0; i < 4; i++)
    #pragma unroll
    for (int j = 0; j < 4; j++) acc[i][j] = (f32x4){0.f,0.f,0.f,0.f};

  const int r0 = tid >> 2, c8 = (tid & 3) * 8;
  const int r1 = r0 + 64;

  #define GSTAGE(cn, kk)                                                     \
    do {                                                                     \
      gl2lds16(A  + (size_t)(m0 + r0)*DM + (kk) + c8, &As[cn][r0][c8]);      \
      gl2lds16(A  + (size_t)(m0 + r1)*DM + (kk) + c8, &As[cn][r1][c8]);      \
      gl2lds16(Bt + (size_t)(n0 + r0)*DM + (kk) + c8, &Bs[cn][r0][c8]);      \
      gl2lds16(Bt + (size_t)(n0 + r1)*DM + (kk) + c8, &Bs[cn][r1][c8]);      \
    } while (0)

  GSTAGE(0, 0);
  __syncthreads();

  int cb = 0;
  for (int k0 = 0; k0 < DM; k0 += 32) {
    if (k0 + 32 < DM) GSTAGE(cb ^ 1, k0 + 32);

    short8 af[4], bf[4];
    #pragma unroll
    for (int mb = 0; mb < 4; mb++) af[mb] = *(const short8*)&As[cb][wm*64 + mb*16 + ln][quad*8];
    #pragma unroll
    for (int nb = 0; nb < 4; nb++) bf[nb] = *(const short8*)&Bs[cb][wn*64 + nb*16 + ln][quad*8];
    #pragma unroll
    for (int mb = 0; mb < 4; mb++)
      #pragma unroll
      for (int nb = 0; nb < 4; nb++)
        acc[mb][nb] = MFMA16(af[mb], bf[nb], acc[mb][nb], 0, 0, 0);

    __syncthreads();   // vmcnt(0): drains NEXT-tile stage (covered by compute)
    cb ^= 1;
  }
  #undef GSTAGE

  const int nc = n0 + wn*64;
  int kind, head;
  if (nc < 1024)      { kind = 0; head = nc >> 6;          }
  else if (nc < 1280) { kind = 1; head = (nc - 1024) >> 6; }
  else                { kind = 2; head = (nc - 1280) >> 6; }

  if (kind == 2) {
    #pragma unroll
    for (int mb = 0; mb < 4; mb++) {
      const int m = m0 + wm*64 + mb*16 + quad*4;
      const int t = m & (SEQN-1), b = m >> 12;
      #pragma unroll
      for (int nb = 0; nb < 4; nb++) {
        int d = nb*16 + ln;
        ushort4 pk;
        pk.x = f2bf(acc[mb][nb][0]); pk.y = f2bf(acc[mb][nb][1]);
        pk.z = f2bf(acc[mb][nb][2]); pk.w = f2bf(acc[mb][nb][3]);
        *(ushort4*)&Vo[(((size_t)(b*HKVn + head))*HDn + d)*SEQN + t] = pk;
      }
    }
  } else {
    #pragma unroll
    for (int mb = 0; mb < 4; mb++) {
      #pragma unroll
      for (int nb = 0; nb < 4; nb++) {
        #pragma unroll
        for (int r = 0; r < 4; r++) {
          int m = m0 + wm*64 + mb*16 + quad*4 + r;
          int t = m & (SEQN-1), b = m >> 12;
          int d = nb*16 + ln;
          float v = acc[mb][nb][r];
          float partner = (nb < 2) ? -acc[mb][nb+2][r] : acc[mb][nb-2][r];
          float cv = ct[t*HDn + d], sv = st[t*HDn + d];
          float o = v*cv + partner*sv;
          if (kind == 0) Qo[(((size_t)(b*HQn  + head))*SEQN + t)*HDn + d] = f2bf(o * QSCALE);
          else           Ko[(((size_t)(b*HKVn + head))*SEQN + t)*HDn + d] = f2bf(o);
        }
      }
    }
  }
}

// ---------------------------------------------------------------------------
// Kernel 2: flash attention — ROUND-7 VERSION VERBATIM (154-155 us, verified
// 4x): async gl2lds staging, XOR-swizzled unpadded double buffers, 1
// barrier/tile, permlane-free K staging interleave, MFMA-of-ones row-sum,
// setprio around MFMA clusters.
// ---------------------------------------------------------------------------
__global__ __launch_bounds__(256, 4) void attn_k(
    const unsigned short* __restrict__ Q, const unsigned short* __restrict__ K,
    const unsigned short* __restrict__ Vt, unsigned short* __restrict__ AO)
{
  __shared__ __align__(16) short kb[2][64][64];   // 8 KB per buf
  __shared__ __align__(16) short vb[2][64][64];   // 8 KB per buf

  const int id  = blockIdx.x;
  const int bhv = id & 7;               // XCD-affine: XCD (id%8) owns one (b,hv)
  const int b   = bhv >> 2, hv = bhv & 3;
  const int rem = id >> 3;
  const int qt  = rem & 31;
  const int h   = hv*4 + (rem >> 5);
  const int q0  = qt * 128;

  const int tid = threadIdx.x, lane = tid & 63, w = tid >> 6;
  const int ln = lane & 15, quad = lane >> 4;

  const unsigned short* Qp = Q + (((size_t)(b*HQn + h))*SEQN + q0 + w*32) * HDn;
  const unsigned short* Kp = K + ((size_t)(b*HKVn + hv))*SEQN * HDn;
  const unsigned short* Vp = Vt + ((size_t)(b*HKVn + hv))*HDn * SEQN;

  short8 qf[2][2];
  qf[0][0] = *(const short8*)(Qp + ln*HDn + quad*8);
  qf[0][1] = *(const short8*)(Qp + ln*HDn + 32 + quad*8);
  qf[1][0] = *(const short8*)(Qp + (16+ln)*HDn + quad*8);
  qf[1][1] = *(const short8*)(Qp + (16+ln)*HDn + 32 + quad*8);

  short8 ones;
  #pragma unroll
  for (int j = 0; j < 8; j++) ones[j] = (short)0x3F80;   // bf16 1.0

  f32x4 o[2][4], lacc[2];
  #pragma unroll
  for (int g = 0; g < 2; g++) {
    #pragma unroll
    for (int i = 0; i < 4; i++) o[g][i] = (f32x4){0.f,0.f,0.f,0.f};
    lacc[g] = (f32x4){0.f,0.f,0.f,0.f};
  }

  // --- staging geometry: waves 0,1 stage K; waves 2,3 stage V. ---
  const int w2   = w & 1;        // half (rows 0-31 / 32-63)
  const int lrow = lane >> 3;    // row within 8-row chunk (== row&7)
  const int slin = lane & 7;     // linear 16B slot within row
  const int sK   = slin ^ lrow;  // swizzled source slot (involution)

  // K uses the PERMLANE-FREE interleave (round 7, verified):
  // kb row R = w2*32 + i*8 + lrow holds key_stage(R)
  //   = 32*w2 + 16*(i&1) + 8*(lrow>>2) + 4*(i>>1) + (lrow&3)
  int kkey[4]; size_t vrow[4];
  #pragma unroll
  for (int i = 0; i < 4; i++) {
    kkey[i] = 32*w2 + 16*(i & 1) + 8*(lrow >> 2) + 4*(i >> 1) + (lrow & 3);
    vrow[i] = (size_t)(w2*32 + i*8 + lrow) * SEQN;
  }

  #define STAGE(cn, kts)                                                     \
    do {                                                                     \
      if (w < 2) {                                                           \
        _Pragma("unroll")                                                    \
        for (int i = 0; i < 4; i++)                                          \
          gl2lds16(Kp + (size_t)((kts) + kkey[i])*HDn + sK*8,                \
                   &kb[cn][w2*32 + i*8][0]);                                 \
      } else {                                                               \
        _Pragma("unroll")                                                    \
        for (int i = 0; i < 4; i++)                                          \
          gl2lds16(Vp + vrow[i] + (kts) + sK*8,                              \
                   &vb[cn][w2*32 + i*8][0]);                                 \
      }                                                                      \
    } while (0)

  // swizzled read offsets (shorts within a row); row&7 == ln&7 for all reads
  const int swz0 = (( quad      ^ (ln & 7)) * 8);
  const int swz1 = (((quad + 4) ^ (ln & 7)) * 8);

  STAGE(0, 0);
  __syncthreads();

  int c = 0;
  for (int kt = 0; kt < SEQN; kt += 64) {
    if (kt + 64 < SEQN) STAGE(c ^ 1, kt + 64);

    // phase 1: swapped QK^T for both g, K fragments read once (8 ds_read_b128)
    // s[g][nb][r] = S[key = 32*(nb>>1) + 8*quad + 4*(nb&1) + r][qrow = ln]
    f32x4 s[2][4];
    __builtin_amdgcn_s_setprio(1);
    #pragma unroll
    for (int nb = 0; nb < 4; nb++) {
      short8 k0 = *(const short8*)&kb[c][nb*16 + ln][swz0];
      short8 k1 = *(const short8*)&kb[c][nb*16 + ln][swz1];
      f32x4 t0 = (f32x4){0.f,0.f,0.f,0.f};
      t0 = MFMA16(k0, qf[0][0], t0, 0, 0, 0);
      t0 = MFMA16(k1, qf[0][1], t0, 0, 0, 0);
      s[0][nb] = t0;
      f32x4 t1 = (f32x4){0.f,0.f,0.f,0.f};
      t1 = MFMA16(k0, qf[1][0], t1, 0, 0, 0);
      t1 = MFMA16(k1, qf[1][1], t1, 0, 0, 0);
      s[1][nb] = t1;
    }
    __builtin_amdgcn_s_setprio(0);

    // exp2 + cvt_pk: PV A-fragments directly from the lane's own registers
    short8 pf[2][2];
    #pragma unroll
    for (int g = 0; g < 2; g++) {
      #pragma unroll
      for (int k2 = 0; k2 < 2; k2++) {
        union { short8 s8; unsigned u[4]; } f;
        f.u[0] = pk_bf2(EXP2F(s[g][2*k2  ][0]), EXP2F(s[g][2*k2  ][1]));
        f.u[1] = pk_bf2(EXP2F(s[g][2*k2  ][2]), EXP2F(s[g][2*k2  ][3]));
        f.u[2] = pk_bf2(EXP2F(s[g][2*k2+1][0]), EXP2F(s[g][2*k2+1][1]));
        f.u[3] = pk_bf2(EXP2F(s[g][2*k2+1][2]), EXP2F(s[g][2*k2+1][3]));
        pf[g][k2] = f.s8;
      }
    }

    // phase 2: P x V^T for both g, V fragments read once (8 ds_read_b128)
    __builtin_amdgcn_s_setprio(1);
    #pragma unroll
    for (int db = 0; db < 4; db++) {
      short8 v0 = *(const short8*)&vb[c][db*16 + ln][swz0];
      short8 v1 = *(const short8*)&vb[c][db*16 + ln][swz1];
      o[0][db] = MFMA16(pf[0][0], v0, o[0][db], 0, 0, 0);
      o[0][db] = MFMA16(pf[0][1], v1, o[0][db], 0, 0, 0);
      o[1][db] = MFMA16(pf[1][0], v0, o[1][db], 0, 0, 0);
      o[1][db] = MFMA16(pf[1][1], v1, o[1][db], 0, 0, 0);
    }
    lacc[0] = MFMA16(pf[0][0], ones, lacc[0], 0, 0, 0);
    lacc[0] = MFMA16(pf[0][1], ones, lacc[0], 0, 0, 0);
    lacc[1] = MFMA16(pf[1][0], ones, lacc[1], 0, 0, 0);
    lacc[1] = MFMA16(pf[1][1], ones, lacc[1], 0, 0, 0);
    __builtin_amdgcn_s_setprio(0);

    __syncthreads();   // vmcnt(0): drains next-tile stage (covered by compute)
    c ^= 1;
  }
  #undef STAGE

  #pragma unroll
  for (int g = 0; g < 2; g++) {
    float inv[4];
    #pragma unroll
    for (int r = 0; r < 4; r++) inv[r] = 1.0f / lacc[g][r];
    #pragma unroll
    for (int db = 0; db < 4; db++) {
      #pragma unroll
      for (int r = 0; r < 4; r++) {
        int gq = q0 + w*32 + g*16 + quad*4 + r;
        int d  = db*16 + ln;
        AO[(((size_t)(b*SEQN + gq))*HQn + h)*HDn + d] = f2bf(o[g][db][r] * inv[r]);
      }
    }
  }
}

// ---------------------------------------------------------------------------
// Kernel 3: output projection — R11 double-buffer + 1-barrier version.
// ---------------------------------------------------------------------------
__global__ __launch_bounds__(256) void oproj2_k(
    const unsigned short* __restrict__ A, const unsigned short* __restrict__ Bt,
    float* __restrict__ out)
{
  __shared__ __align__(16) short As[2][128][32];
  __shared__ __align__(16) short Bs[2][128][32];

  const int m0 = blockIdx.x * 128, n0 = blockIdx.y * 128;
  const int tid = threadIdx.x, lane = tid & 63, w = tid >> 6;
  const int wm = w >> 1, wn = w & 1;
  const int ln = lane & 15, quad = lane >> 4;

  f32x4 acc[4][4];
  #pragma unroll
  for (int i = 0; i < 4; i++)
    #pragma unroll
    for (int j = 0; j < 4; j++) acc[i][j] = (f32x4){0.f,0.f,0.f,0.f};

  const int r0 = tid >> 2, c8 = (tid & 3) * 8;
  const int r1 = r0 + 64;

  #define GSTAGE(cn, kk)                                                     \
    do {                                                                     \
      gl2lds16(A  + (size_t)(m0 + r0)*DM + (kk) + c8, &As[cn][r0][c8]);      \
      gl2lds16(A  + (size_t)(m0 + r1)*DM + (kk) + c8, &As[cn][r1][c8]);      \
      gl2lds16(Bt + (size_t)(n0 + r0)*DM + (kk) + c8, &Bs[cn][r0][c8]);      \
      gl2lds16(Bt + (size_t)(n0 + r1)*DM + (kk) + c8, &Bs[cn][r1][c8]);      \
    } while (0)

  GSTAGE(0, 0);
  __syncthreads();

  int cb = 0;
  for (int k0 = 0; k0 < DM; k0 += 32) {
    if (k0 + 32 < DM) GSTAGE(cb ^ 1, k0 + 32);

    short8 af[4], bf[4];
    #pragma unroll
    for (int mb = 0; mb < 4; mb++) af[mb] = *(const short8*)&As[cb][wm*64 + mb*16 + ln][quad*8];
    #pragma unroll
    for (int nb = 0; nb < 4; nb++) bf[nb] = *(const short8*)&Bs[cb][wn*64 + nb*16 + ln][quad*8];
    #pragma unroll
    for (int mb = 0; mb < 4; mb++)
      #pragma unroll
      for (int nb = 0; nb < 4; nb++)
        acc[mb][nb] = MFMA16(af[mb], bf[nb], acc[mb][nb], 0, 0, 0);

    __syncthreads();   // vmcnt(0): drains NEXT-tile stage (covered by compute)
    cb ^= 1;
  }
  #undef GSTAGE

  #pragma unroll
  for (int mb = 0; mb < 4; mb++) {
    #pragma unroll
    for (int nb = 0; nb < 4; nb++) {
      #pragma unroll
      for (int r = 0; r < 4; r++) {
        int m = m0 + wm*64 + mb*16 + quad*4 + r;
        int c = n0 + wn*64 + nb*16 + ln;
        out[(size_t)m*DM + c] = acc[mb][nb][r];
      }
    }
  }
}

// ---------------------------------------------------------------------------
extern "C" void kernel_launch(void* const* d_in, const int* in_sizes, int n_in,
                              void* d_out, int out_size, void* d_ws, size_t ws_size,
                              hipStream_t stream) {
  const float* x  = (const float*)d_in[0];
  const float* Wq = (const float*)d_in[1];
  const float* Wk = (const float*)d_in[2];
  const float* Wv = (const float*)d_in[3];
  const float* Wo = (const float*)d_in[4];
  float* out = (float*)d_out;

  // workspace layout (47 MB). AO aliases xb (xb dead after qkv2_k).
  char* ws = (char*)d_ws;
  float* cos_t = (float*)ws;                                   // 1 MB
  float* sin_t = cos_t + SEQN*HDn;                             // 1 MB
  unsigned short* xb     = (unsigned short*)(sin_t + SEQN*HDn);   // 16 MB
  unsigned short* AO     = xb;                                    // alias
  unsigned short* Wqkv_t = xb + (size_t)NB*SEQN*DM;               // 3 MB
  unsigned short* Wot    = Wqkv_t + (size_t)NPACK*DM;             // 2 MB
  unsigned short* Qb     = Wot + (size_t)DM*DM;                   // 16 MB
  unsigned short* Kb     = Qb + (size_t)NB*HQn *SEQN*HDn;         // 4 MB
  unsigned short* Vb     = Kb + (size_t)NB*HKVn*SEQN*HDn;         // 4 MB

  hipLaunchKernelGGL(prep_k, dim3(6144), dim3(256), 0, stream,
                     x, Wq, Wk, Wv, Wo, cos_t, sin_t, xb, Wqkv_t, Wot);
  hipLaunchKernelGGL(qkv2_k, dim3(64, 12), dim3(256), 0, stream,
                     xb, Wqkv_t, cos_t, sin_t, Qb, Kb, Vb);
  hipLaunchKernelGGL(attn_k, dim3(1024), dim3(256), 0, stream,
                     Qb, Kb, Vb, AO);
  hipLaunchKernelGGL(oproj2_k, dim3(64, 8), dim3(256), 0, stream,
                     AO, Wot, out);
}